// Round 8
// baseline (467.638 us; speedup 1.0000x reference)
//
#include <hip/hip_runtime.h>

// Problem constants (fixed by setup_inputs in the reference):
//   k,v: [B=2, C=128, Hc=48, Wc=48] fp32; NUM_HEADS=8 -> hd=16
//   WINDOW=5, DILATION=1 -> K=25 offsets, r=2
//   query grid 96x96, scale_factor=2
// Outputs (flat, concatenated):
//   out0 k_nb  [2,8,25,16,96,96]  = 58,982,400 floats
//   out1 v_nb  [2,8,25,16,96,96]  = 58,982,400 floats
//   out2 mask  [2,8,25,96,96]     =  3,686,400 floats (bool -> 0.0/1.0)

#define KV_ELEMS  58982400LL
#define MASK_OFF  117964800LL

typedef float f32x4 __attribute__((ext_vector_type(4)));

// A/B vs Round-7 (465 us): IDENTICAL structure; stores emitted as
//   global_store_dwordx4 ... sc0 sc1 nt
// (system-scope + non-temporal). Theory: kernel stores suffer L2
// write-allocate (RFO) doubling HBM traffic to ~973 MB -> 155 us at the
// fill's 6.27 TB/s — the exact observed residual. sc0 sc1 forecloses
// line allocation; nt marks streaming. The fill (FETCH 14.5 KB on 1.9 GB
// written) demonstrates the no-allocate write path exists.
__device__ __forceinline__ void store_wt(float* p, f32x4 v) {
    asm volatile("global_store_dwordx4 %0, %1, off sc0 sc1 nt"
                 :: "v"(p), "v"(v) : "memory");
}

__global__ __launch_bounds__(256) void fused_expand_kernel(
    const float* __restrict__ k, const float* __restrict__ v,
    float* __restrict__ out_k, float* __restrict__ out_v,
    float* __restrict__ out_m) {
    const int t  = blockIdx.x * 256 + threadIdx.x;
    const int kk = blockIdx.y;           // 0..24
    const int z  = blockIdx.z;           // b*8+h, 0..15

    const int q  = t / 24;               // = d*96 + y
    const int x4 = t - q * 24;
    const int d  = q / 96;
    const int y  = q - d * 96;

    // wave-uniform -> scalar unit
    const int kq = kk / 5;
    const int dy = kq - 2;
    const int dx = kk - kq * 5 - 2;

    const int yy  = (y >> 1) + dy;       // coarse row + offset
    const bool vy = (unsigned)yy < 48u;
    const int xc0 = 2 * x4 + dx;         // coarse col for out x = 4*x4, 4*x4+1
    const int xc1 = xc0 + 1;             // coarse col for out x = 4*x4+2, 4*x4+3
    const bool v0 = vy && ((unsigned)xc0 < 48u);
    const bool v1 = vy && ((unsigned)xc1 < 48u);

    // Clamp indices, load unconditionally, select to 0 afterwards (branchless).
    const int yc = vy ? yy : 0;
    const int x0 = min(max(xc0, 0), 47);
    const int x1 = min(max(xc1, 0), 47);

    const int base = ((z * 16 + d) * 48 + yc) * 48;   // z*16+d = channel 0..255
    float k0 = k[base + x0];
    float k1 = k[base + x1];
    float w0 = v[base + x0];
    float w1 = v[base + x1];
    k0 = v0 ? k0 : 0.0f;
    k1 = v1 ? k1 : 0.0f;
    w0 = v0 ? w0 : 0.0f;
    w1 = v1 ? w1 : 0.0f;

    const int slice = z * 25 + kk;
    const long long o = (long long)slice * 36864 + t;
    store_wt(out_k + 4 * o, (f32x4){k0, k0, k1, k1});
    store_wt(out_v + 4 * o, (f32x4){w0, w0, w1, w1});

    if (blockIdx.x < 9) {  // block-uniform: exactly the d==0 blocks (t < 2304)
        const float m0 = v0 ? 1.0f : 0.0f;
        const float m1 = v1 ? 1.0f : 0.0f;
        store_wt(out_m + 4 * ((long long)slice * 2304 + t),
                 (f32x4){m0, m0, m1, m1});
    }
}

extern "C" void kernel_launch(void* const* d_in, const int* in_sizes, int n_in,
                              void* d_out, int out_size, void* d_ws, size_t ws_size,
                              hipStream_t stream) {
    const float* k = (const float*)d_in[0];
    const float* v = (const float*)d_in[1];
    float* out = (float*)d_out;
    float* out_k = out;
    float* out_v = out + KV_ELEMS;
    float* out_m = out + MASK_OFF;

    // 36864 threads per (kk, z) slice = 144 blocks x 256; grid (144, 25, 16)
    fused_expand_kernel<<<dim3(144, 25, 16), 256, 0, stream>>>(
        k, v, out_k, out_v, out_m);
}